// Round 10
// baseline (407.350 us; speedup 1.0000x reference)
//
#include <hip/hip_runtime.h>

// Round 10: gemm latency round. R9 forensics: 2100 cyc/block-iter vs 512 cyc
// MFMA payload (MfmaUtil 24%). Root cause: prefetch consume-distance = one
// MFMA phase (~600 cyc) < HBM latency (~900) -> vmcnt stall on the barrier
// critical path every iter. Fixes: (1) 2-deep register prefetch ring for A
// (HBM), 1-deep for W (L2-resident); (2) k-permuted LDS layout p=kh*16+s*4+j
// -> frag reads become 8 ds_read_b128/iter/wave (was 16 b64), conflict-free
// at stride 40 (20 dw: starts 20r mod 32 x 4dw tile all 32 banks).
// Attention unchanged (round-8 version, verified). fp32 in/out; f16 ws.

using f16    = _Float16;
using f16x4  = __attribute__((ext_vector_type(4))) _Float16;
using f16x8  = __attribute__((ext_vector_type(8))) _Float16;
using f32x4  = __attribute__((ext_vector_type(4))) float;
using f32x16 = __attribute__((ext_vector_type(16))) float;

static constexpr int S = 1024, Dm = 1024, NH = 16, HD = 64;

#if __has_builtin(__builtin_amdgcn_mfma_f32_32x32x8f16)
#define USE_MFMA32 1
#define MFMA32(ACC, A_, B_) \
    (ACC) = __builtin_amdgcn_mfma_f32_32x32x8f16((A_), (B_), (ACC), 0, 0, 0)
#else
#define USE_MFMA32 0
#endif
#if __has_builtin(__builtin_amdgcn_mfma_f32_16x16x16f16)
#define USE_MFMA 1
#define MFMA16(ACC, A_, B_) \
    (ACC) = __builtin_amdgcn_mfma_f32_16x16x16f16((A_), (B_), (ACC), 0, 0, 0)
#else
#define USE_MFMA 0
#endif

#define LO4(v) __builtin_shufflevector((v), (v), 0, 1, 2, 3)
#define HI4(v) __builtin_shufflevector((v), (v), 4, 5, 6, 7)

__device__ __forceinline__ f16x4 cvt4(float4 a) {
    f16x4 r; r[0] = (f16)a.x; r[1] = (f16)a.y; r[2] = (f16)a.z; r[3] = (f16)a.w;
    return r;
}
// attn hd permutation (K16 frags): k=s*16+q*4+j -> q*16+s*4+j
__device__ __forceinline__ int pcol64(int k) {
    return ((k >> 2) & 3) * 16 + ((k >> 4) << 2) + (k & 3);
}

// mode 0: [B,H,S,HD] f16 hd-permuted; 1: [B,H,HD,S] f16; 2: fp32 row-major
__device__ __forceinline__ void store_out(void* out, int mode, int m, int n, float v) {
    if (mode == 2) {
        ((float*)out)[(size_t)m * Dm + n] = v;
    } else {
        const int b_ = m >> 10, s_ = m & 1023, h_ = n >> 6, hd_ = n & 63;
        const size_t idx = (mode == 0)
            ? (((size_t)(b_ * NH + h_) * S + s_) * HD + pcol64(hd_))
            : (((size_t)(b_ * NH + h_) * HD + hd_) * S + s_);
        ((f16*)out)[idx] = (f16)v;
    }
}

// ---------------------------------------------------------------------------
// out = relu(A @ W^T + bias). 128x128 tile, BK=32, dbuf LDS, 1 barrier/iter.
// GEMM-k permutation inside a BK=32 row: k = s*8 + kh*4 + j  (s 0..3, kh 0..1)
//   -> LDS col p = kh*16 + s*4 + j. Lane (m=l&31, kh=l>>5) reads its 16
//   k-values as two b128s at cols kh*16 and kh*16+8 (s={0,1} and {2,3}).
// A prefetch 2-deep (HBM ~900 cyc), W 1-deep (L2-resident ~200 cyc).
// ---------------------------------------------------------------------------
template <int AF32>
__device__ __forceinline__ void gemm_core(const void* __restrict__ A,
                                          const float* __restrict__ W,
                                          const float* __restrict__ bias,
                                          void* __restrict__ out, int mode)
{
    const int tid = threadIdx.x;
    const int bm = blockIdx.x, bn = blockIdx.y;
#if USE_MFMA32
    // stride 40 f16 = 80 B = 20 dw; b128 frag reads conflict-free (see above);
    // total LDS 2*20480 = 40960 B.
    __shared__ alignas(16) f16 As[2][128][40];
    __shared__ alignas(16) f16 Ws[2][128][40];

    const int lane = tid & 63, wave = tid >> 6;
    const int l31 = lane & 31, khalf = lane >> 5;
    const int wm = wave & 1, wn = wave >> 1;

    // fp32 staging: thread -> rows (tid>>3)+32i, k0=(tid&7)*4 (one s,kh group)
    const int ar = tid >> 3, ac = (tid & 7) * 4;
    const int pA = (((ac >> 2) & 1) << 4) + ((ac >> 3) << 2);   // kh*16+s*4
    // f16 staging: thread -> rows (tid>>2)+64i, k0=(tid&3)*8 (s fixed, kh=0,1)
    const int ar2 = tid >> 2, ac2 = (tid & 3) * 8;
    const int pH = (ac2 >> 3) << 2;                              // s*4

    const float* Af = (const float*)A + (size_t)(bm * 128 + ar) * Dm + ac;
    const f16*   Ah = (const f16*)A   + (size_t)(bm * 128 + ar2) * Dm + ac2;
    const float* Wf = W + (size_t)(bn * 128 + ar) * Dm + ac;

    float4 pa[2][4]; uint4 pah[2][2]; float4 pw[4];
    auto prefA = [&](int d, int k0) {
        if (AF32) {
#pragma unroll
            for (int i = 0; i < 4; ++i) pa[d][i] = *(const float4*)(Af + k0 + (size_t)i * 32 * Dm);
        } else {
#pragma unroll
            for (int i = 0; i < 2; ++i) pah[d][i] = *(const uint4*)(Ah + k0 + (size_t)i * 64 * Dm);
        }
    };
    auto prefW = [&](int k0) {
#pragma unroll
        for (int i = 0; i < 4; ++i) pw[i] = *(const float4*)(Wf + k0 + (size_t)i * 32 * Dm);
    };
    auto stage = [&](int cur, int d) {
        if (AF32) {
#pragma unroll
            for (int i = 0; i < 4; ++i) *(f16x4*)&As[cur][ar + i * 32][pA] = cvt4(pa[d][i]);
        } else {
#pragma unroll
            for (int i = 0; i < 2; ++i) {
                const f16* src = (const f16*)&pah[d][i];
                *(f16x4*)&As[cur][ar2 + i * 64][pH]      = *(const f16x4*)src;       // kh=0
                *(f16x4*)&As[cur][ar2 + i * 64][16 + pH] = *(const f16x4*)(src + 4); // kh=1
            }
        }
#pragma unroll
        for (int i = 0; i < 4; ++i) *(f16x4*)&Ws[cur][ar + i * 32][pA] = cvt4(pw[i]);
    };

    f32x16 acc[2][2] = {};
    prefA(0, 0); prefW(0);
    prefA(1, 32);
    for (int it = 0; it < Dm / 32; ++it) {
        const int cur = it & 1;
        stage(cur, cur);     // A regs slot 'cur' were filled 2 iters ago
        __syncthreads();     // one barrier per iter (dbuf)
        if (it + 2 < Dm / 32) prefA(cur, (it + 2) * 32);
        if (it + 1 < Dm / 32) prefW((it + 1) * 32);

        f16x8 a8[2][2], w8[2][2];   // [g][half]: half 0 -> s={0,1}, 1 -> s={2,3}
#pragma unroll
        for (int g = 0; g < 2; ++g) {
            a8[g][0] = *(const f16x8*)&As[cur][wm * 64 + g * 32 + l31][khalf * 16];
            a8[g][1] = *(const f16x8*)&As[cur][wm * 64 + g * 32 + l31][khalf * 16 + 8];
            w8[g][0] = *(const f16x8*)&Ws[cur][wn * 64 + g * 32 + l31][khalf * 16];
            w8[g][1] = *(const f16x8*)&Ws[cur][wn * 64 + g * 32 + l31][khalf * 16 + 8];
        }
#pragma unroll
        for (int hf = 0; hf < 2; ++hf) {
            MFMA32(acc[0][0], LO4(a8[0][hf]), LO4(w8[0][hf]));
            MFMA32(acc[0][1], LO4(a8[0][hf]), LO4(w8[1][hf]));
            MFMA32(acc[1][0], LO4(a8[1][hf]), LO4(w8[0][hf]));
            MFMA32(acc[1][1], LO4(a8[1][hf]), LO4(w8[1][hf]));
            MFMA32(acc[0][0], HI4(a8[0][hf]), HI4(w8[0][hf]));
            MFMA32(acc[0][1], HI4(a8[0][hf]), HI4(w8[1][hf]));
            MFMA32(acc[1][0], HI4(a8[1][hf]), HI4(w8[0][hf]));
            MFMA32(acc[1][1], HI4(a8[1][hf]), HI4(w8[1][hf]));
        }
    }

    // epilogue. C/D 32x32: col = l31, row = 8*(reg>>2) + 4*khalf + (reg&3)
#pragma unroll
    for (int g2 = 0; g2 < 2; ++g2) {
        const int col = bn * 128 + wn * 64 + g2 * 32 + l31;
        const float bb = bias[col];
#pragma unroll
        for (int g = 0; g < 2; ++g)
#pragma unroll
            for (int blk = 0; blk < 4; ++blk) {
                const int row0 = bm * 128 + wm * 64 + g * 32 + 8 * blk + 4 * khalf;
                if (mode == 1) {   // [B,H,HD,S]: 4 consecutive s -> packed b64
                    const int b_ = row0 >> 10, s_ = row0 & 1023;
                    const int h_ = col >> 6, hd_ = col & 63;
                    f16x4 v;
#pragma unroll
                    for (int r = 0; r < 4; ++r)
                        v[r] = (f16)fmaxf(acc[g][g2][blk * 4 + r] + bb, 0.0f);
                    *(f16x4*)&((f16*)out)[((size_t)(b_ * NH + h_) * HD + hd_) * S + s_] = v;
                } else {
#pragma unroll
                    for (int r = 0; r < 4; ++r)
                        store_out(out, mode, row0 + r, col,
                                  fmaxf(acc[g][g2][blk * 4 + r] + bb, 0.0f));
                }
            }
    }
#else
    // Scalar fallback (correct; slow)
    for (int i = tid; i < 128 * 128; i += 256) {
        const int m = bm * 128 + (i >> 7);
        const int n = bn * 128 + (i & 127);
        float acc = 0.0f;
        for (int k = 0; k < Dm; ++k) {
            const float a = AF32 ? ((const float*)A)[(size_t)m * Dm + k]
                                 : (float)((const f16*)A)[(size_t)m * Dm + k];
            acc = fmaf(a, W[(size_t)n * Dm + k], acc);
        }
        store_out(out, mode, m, n, fmaxf(acc + bias[n], 0.0f));
    }
#endif
}

__global__ __launch_bounds__(256)
void gemm_qkv(const float* __restrict__ q, const float* __restrict__ k,
              const float* __restrict__ v,
              const float* __restrict__ Wq, const float* __restrict__ Wk,
              const float* __restrict__ Wv,
              const float* __restrict__ bq, const float* __restrict__ bk,
              const float* __restrict__ bv,
              f16* __restrict__ qh, f16* __restrict__ kh, f16* __restrict__ vt)
{
    const int z = blockIdx.z;
    const float* A = (z == 0) ? q : (z == 1) ? k : v;
    const float* W = (z == 0) ? Wq : (z == 1) ? Wk : Wv;
    const float* B = (z == 0) ? bq : (z == 1) ? bk : bv;
    f16* O = (z == 0) ? qh : (z == 1) ? kh : vt;
    gemm_core<1>(A, W, B, O, (z == 2) ? 1 : 0);
}

__global__ __launch_bounds__(256)
void gemm_out(const f16* __restrict__ y, const float* __restrict__ Wo,
              const float* __restrict__ bo, float* __restrict__ out)
{
    gemm_core<0>(y, Wo, bo, out, 2);
}

// ---------------------------------------------------------------------------
// Flash attention — UNCHANGED verified version (S^T = K*Q^T trick; qh/kh
// hd-permuted; dbuf K/V; one barrier per kt).
// ---------------------------------------------------------------------------
__global__ __launch_bounds__(256)
void attn_fwd(const f16* __restrict__ qh, const f16* __restrict__ kh,
              const f16* __restrict__ vt, f16* __restrict__ y)
{
    const int bz = blockIdx.x;       // B*H*(S/64) = 1024
    const int qt = bz & 15;
    const int h  = (bz >> 4) & 15;
    const int b  = bz >> 8;
    const size_t head = (size_t)(b * NH + h) * S * HD;

#if USE_MFMA
    __shared__ alignas(16) f16 Ks[2][64][72];
    __shared__ alignas(16) f16 Vs[2][64][72];

    const int tid  = threadIdx.x;
    const int wave = tid >> 6;
    const int lane = tid & 63;
    const int l15  = lane & 15;
    const int quad = lane >> 4;
    const int sr   = tid >> 2;
    const int sc   = (tid & 3) * 16;

    const f16* Qrow = qh + head + (size_t)(qt * 64 + wave * 16 + l15) * HD;
    const f16* Kp   = kh + head;
    const f16* Vp   = vt + head;

    f16x4 aq[4];
    {
        const uint4 q0 = *(const uint4*)(Qrow + quad * 16);
        const uint4 q1 = *(const uint4*)(Qrow + quad * 16 + 8);
        aq[0] = *(f16x4*)((f16*)&q0);
        aq[1] = *(f16x4*)((f16*)&q0 + 4);
        aq[2] = *(f16x4*)((f16*)&q1);
        aq[3] = *(f16x4*)((f16*)&q1 + 4);
    }

    const int qg = qt * 64 + wave * 16 + l15;
    float m_i = -1e30f, l_i = 0.0f;
    f32x4 acc_o[4] = {};

    uint4 pk[2], pv[2];
    auto pref = [&](int kt) {
        const f16* Kr = Kp + (size_t)(kt * 64 + sr) * HD + sc;
        pk[0] = *(const uint4*)Kr;
        pk[1] = *(const uint4*)(Kr + 8);
        const f16* Vr = Vp + (size_t)sr * S + kt * 64 + sc;
        pv[0] = *(const uint4*)Vr;
        pv[1] = *(const uint4*)(Vr + 8);
    };

    pref(0);
    for (int kt = 0; kt <= qt; ++kt) {
        const int cur = kt & 1;
        *(uint4*)&Ks[cur][sr][sc]     = pk[0];
        *(uint4*)&Ks[cur][sr][sc + 8] = pk[1];
        {
            const int sb = (sc >> 4) * 4;
            *(f16x4*)&Vs[cur][sr][0 * 16 + sb] = *(f16x4*)((f16*)&pv[0]);
            *(f16x4*)&Vs[cur][sr][1 * 16 + sb] = *(f16x4*)((f16*)&pv[0] + 4);
            *(f16x4*)&Vs[cur][sr][2 * 16 + sb] = *(f16x4*)((f16*)&pv[1]);
            *(f16x4*)&Vs[cur][sr][3 * 16 + sb] = *(f16x4*)((f16*)&pv[1] + 4);
        }
        __syncthreads();
        if (kt < qt) pref(kt + 1);

        f32x4 accs[4] = {};
#pragma unroll
        for (int t = 0; t < 4; ++t) {
            const f16x8 k8a = *(const f16x8*)&Ks[cur][t * 16 + l15][quad * 16];
            const f16x8 k8b = *(const f16x8*)&Ks[cur][t * 16 + l15][quad * 16 + 8];
            MFMA16(accs[t], LO4(k8a), aq[0]);
            MFMA16(accs[t], HI4(k8a), aq[1]);
            MFMA16(accs[t], LO4(k8b), aq[2]);
            MFMA16(accs[t], HI4(k8b), aq[3]);
        }

        const int key0 = kt * 64 + quad * 4;
#pragma unroll
        for (int t = 0; t < 4; ++t)
#pragma unroll
            for (int r = 0; r < 4; ++r) {
                float sv = accs[t][r] * 0.125f;
                if (key0 + t * 16 + r > qg) sv = -1e9f;
                accs[t][r] = sv;
            }

        float mx = accs[0][0];
#pragma unroll
        for (int t = 0; t < 4; ++t)
#pragma unroll
            for (int r = 0; r < 4; ++r) mx = fmaxf(mx, accs[t][r]);
        mx = fmaxf(mx, __shfl_xor(mx, 16, 64));
        mx = fmaxf(mx, __shfl_xor(mx, 32, 64));
        const float mnew = fmaxf(m_i, mx);
        float sm = 0.0f;
#pragma unroll
        for (int t = 0; t < 4; ++t)
#pragma unroll
            for (int r = 0; r < 4; ++r) {
                const float e = __expf(accs[t][r] - mnew);
                accs[t][r] = e;
                sm += e;
            }
        sm += __shfl_xor(sm, 16, 64);
        sm += __shfl_xor(sm, 32, 64);
        const float alpha = __expf(m_i - mnew);
        l_i = l_i * alpha + sm;
        m_i = mnew;

        f16x4 ap[4];
#pragma unroll
        for (int c = 0; c < 4; ++c) {
            f16x4 v;
#pragma unroll
            for (int j = 0; j < 4; ++j) v[j] = (f16)accs[c][j];
            ap[c] = v;
        }

        float ar[4];
#pragma unroll
        for (int r = 0; r < 4; ++r) ar[r] = __shfl(alpha, quad * 4 + r, 64);
#pragma unroll
        for (int t2 = 0; t2 < 4; ++t2)
#pragma unroll
            for (int r = 0; r < 4; ++r) acc_o[t2][r] *= ar[r];
#pragma unroll
        for (int t2 = 0; t2 < 4; ++t2) {
            const f16x8 v8a = *(const f16x8*)&Vs[cur][t2 * 16 + l15][quad * 16];
            const f16x8 v8b = *(const f16x8*)&Vs[cur][t2 * 16 + l15][quad * 16 + 8];
            MFMA16(acc_o[t2], ap[0], LO4(v8a));
            MFMA16(acc_o[t2], ap[1], HI4(v8a));
            MFMA16(acc_o[t2], ap[2], LO4(v8b));
            MFMA16(acc_o[t2], ap[3], HI4(v8b));
        }
    }

    float lr[4];
#pragma unroll
    for (int r = 0; r < 4; ++r) lr[r] = __shfl(l_i, quad * 4 + r, 64);
#pragma unroll
    for (int t2 = 0; t2 < 4; ++t2)
#pragma unroll
        for (int r = 0; r < 4; ++r) {
            const int srow = qt * 64 + wave * 16 + quad * 4 + r;
            const int dcol = h * 64 + t2 * 16 + l15;
            y[((size_t)b * S + srow) * Dm + dcol] = (f16)(acc_o[t2][r] / lr[r]);
        }
#else
    const int tid = threadIdx.x;
    if (tid < 64) {
        const int q = qt * 64 + tid;
        const f16* Qr = qh + head + (size_t)q * HD;
        float qv[64];
        for (int d = 0; d < 64; ++d) qv[d] = (float)Qr[d];
        float mx = -1e30f;
        for (int key = 0; key <= q; ++key) {
            const f16* Kr = kh + head + (size_t)key * HD;
            float s = 0.0f;
            for (int d = 0; d < 64; ++d) s = fmaf(qv[d], (float)Kr[d], s);
            mx = fmaxf(mx, s * 0.125f);
        }
        float o[64];
        for (int d = 0; d < 64; ++d) o[d] = 0.0f;
        float l = 0.0f;
        for (int key = 0; key <= q; ++key) {
            const f16* Kr = kh + head + (size_t)key * HD;
            float s = 0.0f;
            for (int d = 0; d < 64; ++d) s = fmaf(qv[d], (float)Kr[d], s);
            const float p = __expf(s * 0.125f - mx);
            l += p;
            for (int d = 0; d < 64; ++d)
                o[d] = fmaf(p, (float)vt[head + (size_t)d * S + key], o[d]);
        }
        for (int d = 0; d < 64; ++d)
            y[((size_t)b * S + q) * Dm + h * 64 + d] = (f16)(o[d] / l);
    }
#endif
}

// ---------------------------------------------------------------------------
extern "C" void kernel_launch(void* const* d_in, const int* in_sizes, int n_in,
                              void* d_out, int out_size, void* d_ws, size_t ws_size,
                              hipStream_t stream)
{
    f16* ws = (f16*)d_ws;
    const size_t SEG = (size_t)4 * 1024 * 1024;   // 4M f16 = 8 MB per region
    f16* qh = ws;
    f16* kh = ws + SEG;
    f16* vt = ws + 2 * SEG;
    f16* y  = ws + 3 * SEG;

    gemm_qkv<<<dim3(32, 8, 3), 256, 0, stream>>>(
        (const float*)d_in[0], (const float*)d_in[1], (const float*)d_in[2],
        (const float*)d_in[4], (const float*)d_in[6], (const float*)d_in[8],
        (const float*)d_in[5], (const float*)d_in[7], (const float*)d_in[9],
        qh, kh, vt);
    // d_in[3] = causal tril mask, hardcoded
    attn_fwd<<<dim3(4 * NH * (S / 64)), 256, 0, stream>>>(qh, kh, vt, y);
    gemm_out<<<dim3(32, 8), 256, 0, stream>>>(
        y, (const float*)d_in[10], (const float*)d_in[11], (float*)d_out);
}